// Round 6
// baseline (252.983 us; speedup 1.0000x reference)
//
#include <hip/hip_runtime.h>
#include <math.h>

// Normalization_60095182406123
//
// Separable 4D Gaussian filter of x^2 over axes (freq, orient, y, x):
//   out[c,y,x] = sum g3[df] g3[do] g32[dy] g32[dx] * xsq[c+(df-1)*16+(do-1)*2, y+dy-16, x+dx-16]
// c = img*192 + freq*16 + orient*2 + phase (same flat layout in and out).
//
// Pass 1 (2 phases, ONE barrier):
//   phase1: x^2 + orient(3) + freq(3) fully in registers -> LDS (32 rows x 256 = 32KB)
//           (each thread loads the 15 input rows its output channel needs; the 3x
//            re-read is L2/L3-served)
//   phase2: 32-tap x-blur, 16 outputs/thread -> ws[c,y,x]
//   LDS group swizzle g^=(g>>3)&7 then ^row to kill both the stride-64B pattern
//   and the row-base (1024B = bank 0) aliasing.
// Pass 2: blur_y(32) -> out[c,y,x]
//
// ws needs 768*224*224*4 = 154,140,672 bytes of d_ws.

#define SZW   224
#define PLANE (224*224)
#define PW    256          // floats per LDS row: 16 zero | 224 data | 15 zero | 1 spare

struct GaussArgs {
    float wx[32];   // 32-tap Gaussian (l=32, w=1), matches reference _gauss
    float w30;      // 3-tap edge   = c*exp(-0.5)
    float w31;      // 3-tap center = c
};

// float4-group swizzle: XOR high group bits and row bits into the bank-quad bits
__device__ __forceinline__ int grp(int row, int g) {
    return (g ^ ((g >> 3) & 7)) ^ (row & 7);
}

__global__ __launch_bounds__(512, 8) void pass1_kernel(const float* __restrict__ in,
                                                       float* __restrict__ ws,
                                                       const GaussArgs ga)
{
    __shared__ float s2[32 * PW];   // 32,768 B

    const int tid   = threadIdx.x;
    const int y     = blockIdx.x;          // 0..223
    const int by    = blockIdx.y;          // 0..5
    const int phase = by & 1;
    const int fg    = by >> 1;             // 0..2: output f in [4fg, 4fg+4)
    const int img   = blockIdx.z;          // 0..3

    const float w31 = ga.w31;
    const float w30 = ga.w30;

    // ---- phase 1: x^2, orient 3-tap, freq 3-tap — all in registers -> LDS ----
    {
        const int xp4 = tid & 63;          // x float4-group
        const int oh  = (tid >> 6) & 1;    // orient half: outputs oh*4 .. oh*4+3
        const int fo  = tid >> 7;          // 0..3
        const int f   = fg*4 + fo;         // output freq
        const bool xok = (xp4 >= 4 && xp4 < 60);
        const int x0  = xp4*4 - 16;        // global x of this group

        float4 acc[4];
        #pragma unroll
        for (int k = 0; k < 4; ++k) acc[k] = make_float4(0.f,0.f,0.f,0.f);

        const float* cbase = in + (size_t)(img*192 + phase)*PLANE + y*SZW + x0;

        #pragma unroll
        for (int dj = -1; dj <= 1; ++dj) {
            const int j = f + dj;
            if (j < 0 || j >= 12) continue;          // wave-uniform predicate
            const float wj = (dj == 0) ? w31 : w30;  // freq-conv weight
            // load 5 orient rows (o = oh*3 + i), square
            float4 s[5];
            const float* base = cbase + (size_t)j*16*PLANE + (size_t)oh*6*PLANE;
            #pragma unroll
            for (int i = 0; i < 5; ++i) {
                if (xok) {
                    float4 v = *reinterpret_cast<const float4*>(base + (size_t)i*2*PLANE);
                    s[i] = make_float4(v.x*v.x, v.y*v.y, v.z*v.z, v.w*v.w);
                } else {
                    s[i] = make_float4(0.f,0.f,0.f,0.f);
                }
            }
            // orient 3-tap for the 4 output orients, accumulate with freq weight
            #pragma unroll
            for (int k = 0; k < 4; ++k) {
                float4 c, l, r;
                if (oh) {
                    c = s[k+1]; l = s[k];
                    r = (k < 3) ? s[k+2] : make_float4(0.f,0.f,0.f,0.f);
                } else {
                    c = s[k];
                    l = (k > 0) ? s[k-1] : make_float4(0.f,0.f,0.f,0.f);
                    r = s[k+1];
                }
                acc[k].x = fmaf(wj, fmaf(w31, c.x, w30*(l.x + r.x)), acc[k].x);
                acc[k].y = fmaf(wj, fmaf(w31, c.y, w30*(l.y + r.y)), acc[k].y);
                acc[k].z = fmaf(wj, fmaf(w31, c.z, w30*(l.z + r.z)), acc[k].z);
                acc[k].w = fmaf(wj, fmaf(w31, c.w, w30*(l.w + r.w)), acc[k].w);
            }
        }
        #pragma unroll
        for (int k = 0; k < 4; ++k) {
            const int row = fo*8 + oh*4 + k;
            *reinterpret_cast<float4*>(&s2[row*PW + grp(row, xp4)*4]) = acc[k];
        }
    }
    __syncthreads();

    // ---- phase 2: 32-tap x-blur, 16 outputs/thread ----
    if (tid < 448) {
        const int r   = tid / 14;          // row 0..31 (= fo*8 + o)
        const int xg  = tid - r*14;        // 0..13
        const int fo  = r >> 3;
        const int o   = r & 7;
        const int fo16 = (fg*4 + fo)*16 + o*2;
        const int x0  = xg * 16;           // output x base
        const int rowb = r * PW;
        const int g0  = 4*xg;

        float acc[16];
        #pragma unroll
        for (int j = 0; j < 16; ++j) acc[j] = 0.f;

        #pragma unroll
        for (int t = 0; t < 12; ++t) {
            const float4 q = *reinterpret_cast<const float4*>(
                &s2[rowb + grp(r, g0 + t)*4]);
            #pragma unroll
            for (int e = 0; e < 4; ++e) {
                const int m = 4*t + e;     // window float index 0..47
                const float qv = (e==0)?q.x:(e==1)?q.y:(e==2)?q.z:q.w;
                const int jlo = (m - 31 > 0) ? (m - 31) : 0;
                const int jhi = (m < 15) ? m : 15;
                #pragma unroll
                for (int j = jlo; j <= jhi; ++j)
                    acc[j] = fmaf(ga.wx[m - j], qv, acc[j]);
            }
        }

        float* op = ws + (size_t)(img*192 + phase)*PLANE + y*SZW
                       + (size_t)fo16*PLANE + x0;
        #pragma unroll
        for (int s = 0; s < 4; ++s)
            *reinterpret_cast<float4*>(op + 4*s) =
                make_float4(acc[4*s], acc[4*s+1], acc[4*s+2], acc[4*s+3]);
    }
}

__global__ __launch_bounds__(256) void pass2_kernel(const float* __restrict__ ws,
                                                    float* __restrict__ out,
                                                    const GaussArgs ga)
{
    const int c = blockIdx.x;     // 0..767
    const int x = threadIdx.x;    // column
    if (x >= SZW) return;

    const float* col = ws  + (size_t)c * PLANE + x;
    float*       oc  = out + (size_t)c * PLANE + x;

    float w[47];
    #pragma unroll
    for (int i = 0; i < 47; ++i) {
        int yy = i - 16;
        w[i] = (yy >= 0 && yy < SZW) ? col[yy*SZW] : 0.f;
    }

    #pragma unroll 1
    for (int y0 = 0; y0 < SZW; y0 += 16) {
        float acc[16];
        #pragma unroll
        for (int j = 0; j < 16; ++j) acc[j] = 0.f;
        #pragma unroll
        for (int k = 0; k < 32; ++k) {
            #pragma unroll
            for (int j = 0; j < 16; ++j)
                acc[j] = fmaf(ga.wx[k], w[j+k], acc[j]);
        }
        #pragma unroll
        for (int j = 0; j < 16; ++j) oc[(y0+j)*SZW] = acc[j];

        #pragma unroll
        for (int i = 0; i < 31; ++i) w[i] = w[i+16];
        #pragma unroll
        for (int i = 0; i < 16; ++i) {
            int yy = y0 + 31 + i;
            w[31+i] = (yy < SZW) ? col[yy*SZW] : 0.f;
        }
    }
}

extern "C" void kernel_launch(void* const* d_in, const int* in_sizes, int n_in,
                              void* d_out, int out_size, void* d_ws, size_t ws_size,
                              hipStream_t stream)
{
    const float* x  = (const float*)d_in[0];
    float*      out = (float*)d_out;
    float*      ws  = (float*)d_ws;   // 768*224*224*4 = 154,140,672 B

    // Host-computed Gaussian weights (double precision then rounded to f32 —
    // matches reference _gauss float64 path).
    GaussArgs ga;
    const double c0 = 1.0 / sqrt(2.0 * 3.14159265358979323846);
    for (int k = 0; k < 32; ++k) {
        double t = -1.0 + 2.0 * (double)k / 31.0;
        ga.wx[k] = (float)(c0 * exp(-t * t / 2.0));
    }
    ga.w31 = (float)c0;
    ga.w30 = (float)(c0 * exp(-0.5));

    dim3 g1(SZW, 6, 4);               // (y, phase*freqgroup, img)
    pass1_kernel<<<g1, 512, 0, stream>>>(x, ws, ga);
    pass2_kernel<<<768, 256, 0, stream>>>(ws, out, ga);
}